// Round 1
// baseline (346.743 us; speedup 1.0000x reference)
//
#include <hip/hip_runtime.h>
#include <math.h>

#define DI   2048      // D_INNER
#define DS   16        // D_STATE
#define DTR  128       // DT_RANK
#define NBATCH 2
#define SEQ  2048
#define ROWS (NBATCH*SEQ)   // 4096
#define NE   (DTR + 2*DS)   // 160
#define NC   32             // chunks along L
#define LC   (SEQ/NC)       // 64

// ---------------- GEMM1: x_dbl partials = x @ x_proj_w^T (K-split 2) ----------------
// grid (ROWS/16, 2), 256 thr. out: part[ks][row][e]
__global__ __launch_bounds__(256) void k_gemm1(const float* __restrict__ x,
                                               const float* __restrict__ w,
                                               float* __restrict__ part) {
    __shared__ float xs[32][17];
    __shared__ float wsh[32][161];
    const int rowBase = blockIdx.x * 16;
    const int k0base  = blockIdx.y * (DI/2);
    const int t  = threadIdx.x;
    const int rr = t & 7;    // row pair
    const int g  = t >> 3;   // col group 0..31 (5 cols each)
    const int kk = t & 31;
    const int rs = t >> 5;   // 0..7
    float acc[2][5] = {};
    for (int k0 = k0base; k0 < k0base + DI/2; k0 += 32) {
        #pragma unroll
        for (int i = 0; i < 2; i++) {
            int r = rs + 8*i;
            xs[kk][r] = x[(size_t)(rowBase + r)*DI + k0 + kk];
        }
        #pragma unroll
        for (int j = 0; j < 20; j++) {
            int e = rs + 8*j;
            wsh[kk][e] = w[(size_t)e*DI + k0 + kk];
        }
        __syncthreads();
        #pragma unroll
        for (int k2 = 0; k2 < 32; k2++) {
            float x0 = xs[k2][2*rr], x1 = xs[k2][2*rr+1];
            #pragma unroll
            for (int j = 0; j < 5; j++) {
                float wv = wsh[k2][g*5 + j];
                acc[0][j] = fmaf(x0, wv, acc[0][j]);
                acc[1][j] = fmaf(x1, wv, acc[1][j]);
            }
        }
        __syncthreads();
    }
    #pragma unroll
    for (int i = 0; i < 2; i++) {
        int row = rowBase + 2*rr + i;
        #pragma unroll
        for (int j = 0; j < 5; j++)
            part[((size_t)blockIdx.y*ROWS + row)*NE + g*5 + j] = acc[i][j];
    }
}

// ---------------- reduce K-split partials, split into delta_r / B / C ----------------
__global__ __launch_bounds__(256) void k_split(const float* __restrict__ part,
                                               float* __restrict__ dR,
                                               float* __restrict__ Bm,
                                               float* __restrict__ Cm) {
    int i = blockIdx.x*256 + threadIdx.x;
    if (i >= ROWS*NE) return;
    float v = part[i] + part[(size_t)ROWS*NE + i];
    int row = i / NE, e = i - row*NE;
    if (e < DTR)            dR[(size_t)row*DTR + e] = v;
    else if (e < DTR + DS)  Bm[(size_t)row*DS + (e - DTR)] = v;
    else                    Cm[(size_t)row*DS + (e - DTR - DS)] = v;
}

// ---------------- GEMM2: delta = softplus(dR @ dt_proj_w^T + bias) ----------------
// grid (ROWS/64, DI/64), 256 thr, 4x4 float4 register tiles
__global__ __launch_bounds__(256) void k_gemm2(const float* __restrict__ dR,
                                               const float* __restrict__ wdt,
                                               const float* __restrict__ bias,
                                               float* __restrict__ delta) {
    __shared__ float as[32][68];
    __shared__ float bs[32][68];
    const int mb = blockIdx.x * 64, nb = blockIdx.y * 64;
    const int t  = threadIdx.x;
    const int tm = t >> 4, tn = t & 15;
    const int kk = t & 31, q = t >> 5;   // staging: q 0..7
    float acc[4][4] = {};
    for (int k0 = 0; k0 < DTR; k0 += 32) {
        #pragma unroll
        for (int i = 0; i < 8; i++) {
            int m = q + 8*i;
            as[kk][m] = dR [(size_t)(mb + m)*DTR + k0 + kk];
            bs[kk][m] = wdt[(size_t)(nb + m)*DTR + k0 + kk];
        }
        __syncthreads();
        #pragma unroll
        for (int k2 = 0; k2 < 32; k2++) {
            float4 av = *(const float4*)&as[k2][4*tm];
            float4 bv = *(const float4*)&bs[k2][4*tn];
            float aa[4] = {av.x, av.y, av.z, av.w};
            float bb[4] = {bv.x, bv.y, bv.z, bv.w};
            #pragma unroll
            for (int i = 0; i < 4; i++)
                #pragma unroll
                for (int j = 0; j < 4; j++)
                    acc[i][j] = fmaf(aa[i], bb[j], acc[i][j]);
        }
        __syncthreads();
    }
    #pragma unroll
    for (int i = 0; i < 4; i++) {
        int row = mb + 4*tm + i;
        float4 o;
        float* op = &o.x;
        #pragma unroll
        for (int j = 0; j < 4; j++) {
            int col = nb + 4*tn + j;
            float v = acc[i][j] + bias[col];
            // stable softplus
            op[j] = fmaxf(v, 0.f) + log1pf(__expf(-fabsf(v)));
        }
        *(float4*)&delta[(size_t)row*DI + nb + 4*tn] = o;
    }
}

// ---------------- scan pass 1: per-chunk summaries (A_prod, r) ----------------
// thread = (b, chunk, d). layouts: aprod/rsum/hin = [c][b][n][d]
__global__ __launch_bounds__(256) void k_scan1(const float* __restrict__ delta,
                                               const float* __restrict__ x,
                                               const float* __restrict__ Bm,
                                               const float* __restrict__ A_log,
                                               float* __restrict__ aprod,
                                               float* __restrict__ rsum) {
    int gid = blockIdx.x*256 + threadIdx.x;     // B*NC*DI threads
    int d = gid & (DI-1);
    int rest = gid >> 11;      // 0..63
    int b = rest & 1;
    int c = rest >> 1;         // 0..31
    float An[DS], ap[DS], r[DS];
    #pragma unroll
    for (int n = 0; n < DS; n++) {
        An[n] = -__expf(A_log[d*DS + n]);
        ap[n] = 1.f; r[n] = 0.f;
    }
    const float* dp = delta + (size_t)b*SEQ*DI + d;
    const float* xp = x     + (size_t)b*SEQ*DI + d;
    const float* bp = Bm    + (size_t)b*SEQ*DS;
    const int lbase = c*LC;
    for (int tt = 0; tt < LC; tt++) {
        int l = lbase + tt;
        float dlt = dp[(size_t)l*DI];
        float u   = xp[(size_t)l*DI];
        float du  = dlt * u;
        const float* bv = bp + (size_t)l*DS;
        #pragma unroll
        for (int n = 0; n < DS; n++) {
            float da = __expf(dlt * An[n]);
            r[n]  = fmaf(da, r[n], du * bv[n]);
            ap[n] *= da;
        }
    }
    size_t base = ((size_t)c*NBATCH + b)*DS*DI + d;
    #pragma unroll
    for (int n = 0; n < DS; n++) {
        aprod[base + (size_t)n*DI] = ap[n];
        rsum [base + (size_t)n*DI] = r[n];
    }
}

// ---------------- middle: sequential combine across chunks ----------------
__global__ __launch_bounds__(256) void k_mid(const float* __restrict__ aprod,
                                             const float* __restrict__ rsum,
                                             float* __restrict__ hin) {
    int gid = blockIdx.x*256 + threadIdx.x;     // B*DS*DI threads
    int d = gid & (DI-1);
    int rest = gid >> 11;   // 0..31
    int n = rest & 15;
    int b = rest >> 4;
    float h = 0.f;
    for (int c = 0; c < NC; c++) {
        size_t idx = (((size_t)c*NBATCH + b)*DS + n)*DI + d;
        hin[idx] = h;
        h = fmaf(aprod[idx], h, rsum[idx]);
    }
}

// ---------------- scan pass 2: recompute with chunk-entry states, emit y ----------------
__global__ __launch_bounds__(256) void k_scan2(const float* __restrict__ delta,
                                               const float* __restrict__ x,
                                               const float* __restrict__ Bm,
                                               const float* __restrict__ Cm,
                                               const float* __restrict__ A_log,
                                               const float* __restrict__ Dv,
                                               const float* __restrict__ hin,
                                               float* __restrict__ y) {
    int gid = blockIdx.x*256 + threadIdx.x;
    int d = gid & (DI-1);
    int rest = gid >> 11;
    int b = rest & 1;
    int c = rest >> 1;
    float An[DS], h[DS];
    size_t base = ((size_t)c*NBATCH + b)*DS*DI + d;
    #pragma unroll
    for (int n = 0; n < DS; n++) {
        An[n] = -__expf(A_log[d*DS + n]);
        h[n]  = hin[base + (size_t)n*DI];
    }
    const float Dd = Dv[d];
    const float* dp = delta + (size_t)b*SEQ*DI + d;
    const float* xp = x     + (size_t)b*SEQ*DI + d;
    const float* bp = Bm    + (size_t)b*SEQ*DS;
    const float* cp = Cm    + (size_t)b*SEQ*DS;
    float* yp = y + (size_t)b*SEQ*DI + d;
    const int lbase = c*LC;
    for (int tt = 0; tt < LC; tt++) {
        int l = lbase + tt;
        float dlt = dp[(size_t)l*DI];
        float u   = xp[(size_t)l*DI];
        float du  = dlt * u;
        const float* bv = bp + (size_t)l*DS;
        const float* cv = cp + (size_t)l*DS;
        float acc = 0.f;
        #pragma unroll
        for (int n = 0; n < DS; n++) {
            float da = __expf(dlt * An[n]);
            h[n] = fmaf(da, h[n], du * bv[n]);
            acc  = fmaf(h[n], cv[n], acc);
        }
        yp[(size_t)l*DI] = fmaf(u, Dd, acc);
    }
}

extern "C" void kernel_launch(void* const* d_in, const int* in_sizes, int n_in,
                              void* d_out, int out_size, void* d_ws, size_t ws_size,
                              hipStream_t stream) {
    const float* x     = (const float*)d_in[0];
    const float* A_log = (const float*)d_in[1];
    const float* Dv    = (const float*)d_in[2];
    const float* xpw   = (const float*)d_in[3];
    const float* dtw   = (const float*)d_in[4];
    const float* dtb   = (const float*)d_in[5];
    float* out = (float*)d_out;

    float* ws    = (float*)d_ws;
    float* delta = ws;                                   // ROWS*DI
    float* part  = delta + (size_t)ROWS*DI;              // 2*ROWS*NE
    float* dR    = part  + 2*(size_t)ROWS*NE;            // ROWS*DTR
    float* Bm    = dR    + (size_t)ROWS*DTR;             // ROWS*DS
    float* Cm    = Bm    + (size_t)ROWS*DS;              // ROWS*DS
    float* aprod = Cm    + (size_t)ROWS*DS;              // NC*NBATCH*DS*DI
    float* rsum  = aprod + (size_t)NC*NBATCH*DS*DI;
    float* hin   = rsum  + (size_t)NC*NBATCH*DS*DI;

    k_gemm1<<<dim3(ROWS/16, 2), 256, 0, stream>>>(x, xpw, part);
    k_split<<<(ROWS*NE + 255)/256, 256, 0, stream>>>(part, dR, Bm, Cm);
    k_gemm2<<<dim3(ROWS/64, DI/64), 256, 0, stream>>>(dR, dtw, dtb, delta);
    k_scan1<<<(NBATCH*NC*DI)/256, 256, 0, stream>>>(delta, x, Bm, A_log, aprod, rsum);
    k_mid<<<(NBATCH*DS*DI)/256, 256, 0, stream>>>(aprod, rsum, hin);
    k_scan2<<<(NBATCH*NC*DI)/256, 256, 0, stream>>>(delta, x, Bm, Cm, A_log, Dv, hin, out);
}

// Round 3
// 263.846 us; speedup vs baseline: 1.3142x; 1.3142x over previous
//
#include <hip/hip_runtime.h>
#include <math.h>

#define DI   2048      // D_INNER
#define DS   16        // D_STATE
#define DTR  128       // DT_RANK
#define NBATCH 2
#define SEQ  2048
#define ROWS (NBATCH*SEQ)   // 4096
#define NE   (DTR + 2*DS)   // 160
#define NC   32             // chunks along L
#define LC   (SEQ/NC)       // 64
#define KS1  4              // GEMM1 K-split

typedef float f32x4 __attribute__((ext_vector_type(4)));
typedef short s16x8 __attribute__((ext_vector_type(8)));
typedef short s16x4 __attribute__((ext_vector_type(4)));

__device__ inline short f2bf(float f) {
    unsigned u = __builtin_bit_cast(unsigned, f);
    u += 0x7FFFu + ((u >> 16) & 1u);   // RNE
    return (short)(u >> 16);
}

// ---------------- cast weights to bf16 ----------------
__global__ __launch_bounds__(256) void k_castw(const float* __restrict__ w,
                                               const float* __restrict__ dtw,
                                               short* __restrict__ wb,
                                               short* __restrict__ dtwb) {
    int i = blockIdx.x*256 + threadIdx.x;     // 4 elems each
    if (i < 81920) {                          // 160*2048/4
        float4 v = ((const float4*)w)[i];
        s16x4 o = { f2bf(v.x), f2bf(v.y), f2bf(v.z), f2bf(v.w) };
        *(s16x4*)(wb + 4*i) = o;
    } else if (i < 147456) {                  // + 2048*128/4
        int j = i - 81920;
        float4 v = ((const float4*)dtw)[j];
        s16x4 o = { f2bf(v.x), f2bf(v.y), f2bf(v.z), f2bf(v.w) };
        *(s16x4*)(dtwb + 4*j) = o;
    }
}

// ---------------- GEMM1: part[ks] = x(bf16 in-reg) @ wb^T — no LDS ----------------
__global__ __launch_bounds__(256) void k_gemm1(const float* __restrict__ x,
                                               const short* __restrict__ wb,
                                               float* __restrict__ part) {
    const int wave = blockIdx.x*4 + (threadIdx.x >> 6);
    const int lane = threadIdx.x & 63;
    const int m16 = wave & 255;
    const int ks  = wave >> 8;
    const int r = lane & 15, g = lane >> 4;
    f32x4 acc[10];
    #pragma unroll
    for (int i = 0; i < 10; i++) acc[i] = (f32x4){0.f,0.f,0.f,0.f};

    const float* xp = x + (size_t)(m16*16 + r)*DI + g*8;
    #pragma unroll 2
    for (int kk = 0; kk < 16; ++kk) {
        const int k0 = ks*512 + kk*32;
        float4 xa = *(const float4*)(xp + k0);
        float4 xc = *(const float4*)(xp + k0 + 4);
        s16x8 afrag = { f2bf(xa.x), f2bf(xa.y), f2bf(xa.z), f2bf(xa.w),
                        f2bf(xc.x), f2bf(xc.y), f2bf(xc.z), f2bf(xc.w) };
        const short* bp = wb + (size_t)r*DI + k0 + g*8;
        #pragma unroll
        for (int nf = 0; nf < 10; ++nf) {
            s16x8 bfrag = *(const s16x8*)(bp + (size_t)nf*16*DI);
            acc[nf] = __builtin_amdgcn_mfma_f32_16x16x32_bf16(afrag, bfrag, acc[nf], 0, 0, 0);
        }
    }
    const int orow = m16*16 + g*4;
    #pragma unroll
    for (int nf = 0; nf < 10; ++nf)
        #pragma unroll
        for (int j = 0; j < 4; ++j)
            part[((size_t)ks*ROWS + orow + j)*NE + nf*16 + r] = acc[nf][j];
}

// ---------------- reduce partials, emit dR(bf16) / B / C ----------------
__global__ __launch_bounds__(256) void k_split(const float* __restrict__ part,
                                               short* __restrict__ dRb,
                                               float* __restrict__ Bm,
                                               float* __restrict__ Cm) {
    int i = blockIdx.x*256 + threadIdx.x;
    if (i >= ROWS*NE) return;
    float v = part[i] + part[(size_t)ROWS*NE + i]
            + part[2*(size_t)ROWS*NE + i] + part[3*(size_t)ROWS*NE + i];
    int row = i / NE, e = i - row*NE;
    if (e < DTR)            dRb[(size_t)row*DTR + e] = f2bf(v);
    else if (e < DTR + DS)  Bm[(size_t)row*DS + (e - DTR)] = v;
    else                    Cm[(size_t)row*DS + (e - DTR - DS)] = v;
}

// ---------------- GEMM2: delta = softplus(dRb @ dtwb^T + bias) — no LDS ----------------
__global__ __launch_bounds__(256) void k_gemm2(const short* __restrict__ dRb,
                                               const short* __restrict__ dtwb,
                                               const float* __restrict__ bias,
                                               float* __restrict__ delta) {
    const int wave = blockIdx.x*4 + (threadIdx.x >> 6);
    const int lane = threadIdx.x & 63;
    const int m16 = wave >> 5, nt = wave & 31;
    const int r = lane & 15, g = lane >> 4;

    s16x8 a[4];
    const short* ap = dRb + (size_t)(m16*16 + r)*DTR + g*8;
    #pragma unroll
    for (int ks = 0; ks < 4; ++ks) a[ks] = *(const s16x8*)(ap + ks*32);

    f32x4 acc[4];
    #pragma unroll
    for (int i = 0; i < 4; i++) acc[i] = (f32x4){0.f,0.f,0.f,0.f};

    #pragma unroll
    for (int nf = 0; nf < 4; ++nf) {
        const short* bp = dtwb + (size_t)(nt*64 + nf*16 + r)*DTR + g*8;
        #pragma unroll
        for (int ks = 0; ks < 4; ++ks) {
            s16x8 b = *(const s16x8*)(bp + ks*32);
            acc[nf] = __builtin_amdgcn_mfma_f32_16x16x32_bf16(a[ks], b, acc[nf], 0, 0, 0);
        }
    }
    const int orow = m16*16 + g*4;
    #pragma unroll
    for (int nf = 0; nf < 4; ++nf) {
        const int col = nt*64 + nf*16 + r;
        const float bb = bias[col];
        #pragma unroll
        for (int j = 0; j < 4; ++j) {
            float v = acc[nf][j] + bb;
            delta[(size_t)(orow + j)*DI + col] = fmaxf(v, 0.f) + log1pf(__expf(-fabsf(v)));
        }
    }
}

// ---------------- scan pass 1 ----------------
__global__ __launch_bounds__(256) void k_scan1(const float* __restrict__ delta,
                                               const float* __restrict__ x,
                                               const float* __restrict__ Bm,
                                               const float* __restrict__ A_log,
                                               float* __restrict__ aprod,
                                               float* __restrict__ rsum) {
    int gid = blockIdx.x*256 + threadIdx.x;
    int d = gid & (DI-1);
    int rest = gid >> 11;
    int b = rest & 1;
    int c = rest >> 1;
    float An[DS], ap[DS], r[DS];
    #pragma unroll
    for (int n = 0; n < DS; n++) {
        An[n] = -__expf(A_log[d*DS + n]);
        ap[n] = 1.f; r[n] = 0.f;
    }
    const float* dp = delta + (size_t)b*SEQ*DI + d;
    const float* xp = x     + (size_t)b*SEQ*DI + d;
    const float* bp = Bm    + (size_t)b*SEQ*DS;
    const int lbase = c*LC;
    for (int tt = 0; tt < LC; tt++) {
        int l = lbase + tt;
        float dlt = dp[(size_t)l*DI];
        float u   = xp[(size_t)l*DI];
        float du  = dlt * u;
        const float* bv = bp + (size_t)l*DS;
        #pragma unroll
        for (int n = 0; n < DS; n++) {
            float da = __expf(dlt * An[n]);
            r[n]  = fmaf(da, r[n], du * bv[n]);
            ap[n] *= da;
        }
    }
    size_t base = ((size_t)c*NBATCH + b)*DS*DI + d;
    #pragma unroll
    for (int n = 0; n < DS; n++) {
        aprod[base + (size_t)n*DI] = ap[n];
        rsum [base + (size_t)n*DI] = r[n];
    }
}

// ---------------- middle combine ----------------
__global__ __launch_bounds__(256) void k_mid(const float* __restrict__ aprod,
                                             const float* __restrict__ rsum,
                                             float* __restrict__ hin) {
    int gid = blockIdx.x*256 + threadIdx.x;
    int d = gid & (DI-1);
    int rest = gid >> 11;
    int n = rest & 15;
    int b = rest >> 4;
    float h = 0.f;
    for (int c = 0; c < NC; c++) {
        size_t idx = (((size_t)c*NBATCH + b)*DS + n)*DI + d;
        hin[idx] = h;
        h = fmaf(aprod[idx], h, rsum[idx]);
    }
}

// ---------------- scan pass 2 ----------------
__global__ __launch_bounds__(256) void k_scan2(const float* __restrict__ delta,
                                               const float* __restrict__ x,
                                               const float* __restrict__ Bm,
                                               const float* __restrict__ Cm,
                                               const float* __restrict__ A_log,
                                               const float* __restrict__ Dv,
                                               const float* __restrict__ hin,
                                               float* __restrict__ y) {
    int gid = blockIdx.x*256 + threadIdx.x;
    int d = gid & (DI-1);
    int rest = gid >> 11;
    int b = rest & 1;
    int c = rest >> 1;
    float An[DS], h[DS];
    size_t base = ((size_t)c*NBATCH + b)*DS*DI + d;
    #pragma unroll
    for (int n = 0; n < DS; n++) {
        An[n] = -__expf(A_log[d*DS + n]);
        h[n]  = hin[base + (size_t)n*DI];
    }
    const float Dd = Dv[d];
    const float* dp = delta + (size_t)b*SEQ*DI + d;
    const float* xp = x     + (size_t)b*SEQ*DI + d;
    const float* bp = Bm    + (size_t)b*SEQ*DS;
    const float* cp = Cm    + (size_t)b*SEQ*DS;
    float* yp = y + (size_t)b*SEQ*DI + d;
    const int lbase = c*LC;
    for (int tt = 0; tt < LC; tt++) {
        int l = lbase + tt;
        float dlt = dp[(size_t)l*DI];
        float u   = xp[(size_t)l*DI];
        float du  = dlt * u;
        const float* bv = bp + (size_t)l*DS;
        const float* cv = cp + (size_t)l*DS;
        float acc = 0.f;
        #pragma unroll
        for (int n = 0; n < DS; n++) {
            float da = __expf(dlt * An[n]);
            h[n] = fmaf(da, h[n], du * bv[n]);
            acc  = fmaf(h[n], cv[n], acc);
        }
        yp[(size_t)l*DI] = fmaf(u, Dd, acc);
    }
}

extern "C" void kernel_launch(void* const* d_in, const int* in_sizes, int n_in,
                              void* d_out, int out_size, void* d_ws, size_t ws_size,
                              hipStream_t stream) {
    const float* x     = (const float*)d_in[0];
    const float* A_log = (const float*)d_in[1];
    const float* Dv    = (const float*)d_in[2];
    const float* xpw   = (const float*)d_in[3];
    const float* dtw   = (const float*)d_in[4];
    const float* dtb   = (const float*)d_in[5];
    float* out = (float*)d_out;

    const size_t SCN = (size_t)NC*NBATCH*DS*DI;          // 2,097,152 floats

    float* ws    = (float*)d_ws;
    float* delta = ws;                                   // ROWS*DI floats
    float* unionR= delta + (size_t)ROWS*DI;              // union region start
    float* part  = unionR;                               // KS1*ROWS*NE floats (dead after k_split)
    float* aprod = unionR;                               // aliases part
    float* rsum  = aprod + SCN;
    float* hin   = rsum  + SCN;
    float* uend  = hin   + SCN;                          // 3*SCN > KS1*ROWS*NE -> union = 3*SCN
    float* Bm    = uend;                                 // ROWS*DS
    float* Cm    = Bm + (size_t)ROWS*DS;                 // ROWS*DS
    short* dRb   = (short*)(Cm + (size_t)ROWS*DS);       // ROWS*DTR shorts
    short* wb    = dRb + (size_t)ROWS*DTR;               // 160*2048 shorts
    short* dtwb  = wb  + (size_t)160*2048;               // 2048*128 shorts

    k_castw<<<576, 256, 0, stream>>>(xpw, dtw, wb, dtwb);
    k_gemm1<<<256, 256, 0, stream>>>(x, wb, part);
    k_split<<<(ROWS*NE + 255)/256, 256, 0, stream>>>(part, dRb, Bm, Cm);
    k_gemm2<<<2048, 256, 0, stream>>>(dRb, dtwb, dtb, delta);
    k_scan1<<<(NBATCH*NC*DI)/256, 256, 0, stream>>>(delta, x, Bm, A_log, aprod, rsum);
    k_mid<<<(NBATCH*DS*DI)/256, 256, 0, stream>>>(aprod, rsum, hin);
    k_scan2<<<(NBATCH*NC*DI)/256, 256, 0, stream>>>(delta, x, Bm, Cm, A_log, Dv, hin, out);
}

// Round 4
// 227.907 us; speedup vs baseline: 1.5214x; 1.1577x over previous
//
#include <hip/hip_runtime.h>
#include <math.h>

#define DI   2048      // D_INNER
#define DS   16        // D_STATE
#define DTR  128       // DT_RANK
#define NBATCH 2
#define SEQ  2048
#define ROWS (NBATCH*SEQ)   // 4096
#define NE   (DTR + 2*DS)   // 160
#define NC   32             // chunks along L
#define LC   (SEQ/NC)       // 64
#define KS1  8              // GEMM1 K-split

typedef float f32x4 __attribute__((ext_vector_type(4)));
typedef short s16x8 __attribute__((ext_vector_type(8)));
typedef short s16x4 __attribute__((ext_vector_type(4)));

__device__ inline short f2bf(float f) {
    unsigned u = __builtin_bit_cast(unsigned, f);
    u += 0x7FFFu + ((u >> 16) & 1u);   // RNE
    return (short)(u >> 16);
}

// ---------------- cast weights to bf16 ----------------
__global__ __launch_bounds__(256) void k_castw(const float* __restrict__ w,
                                               const float* __restrict__ dtw,
                                               short* __restrict__ wb,
                                               short* __restrict__ dtwb) {
    int i = blockIdx.x*256 + threadIdx.x;     // 4 elems each
    if (i < 81920) {                          // 160*2048/4
        float4 v = ((const float4*)w)[i];
        s16x4 o = { f2bf(v.x), f2bf(v.y), f2bf(v.z), f2bf(v.w) };
        *(s16x4*)(wb + 4*i) = o;
    } else if (i < 147456) {                  // + 2048*128/4
        int j = i - 81920;
        float4 v = ((const float4*)dtw)[j];
        s16x4 o = { f2bf(v.x), f2bf(v.y), f2bf(v.z), f2bf(v.w) };
        *(s16x4*)(dtwb + 4*j) = o;
    }
}

// ---------------- GEMM1: part[ks] = x(bf16 in-reg) @ wb^T — no LDS, K-split 8 ----------------
__global__ __launch_bounds__(256) void k_gemm1(const float* __restrict__ x,
                                               const short* __restrict__ wb,
                                               float* __restrict__ part) {
    const int wave = blockIdx.x*4 + (threadIdx.x >> 6);   // 0..2047
    const int lane = threadIdx.x & 63;
    const int m16 = wave & 255;
    const int ks  = wave >> 8;                            // 0..7
    const int r = lane & 15, g = lane >> 4;
    f32x4 acc[10];
    #pragma unroll
    for (int i = 0; i < 10; i++) acc[i] = (f32x4){0.f,0.f,0.f,0.f};

    const float* xp = x + (size_t)(m16*16 + r)*DI + g*8;
    #pragma unroll 2
    for (int kk = 0; kk < 8; ++kk) {
        const int k0 = ks*256 + kk*32;
        float4 xa = *(const float4*)(xp + k0);
        float4 xc = *(const float4*)(xp + k0 + 4);
        s16x8 afrag = { f2bf(xa.x), f2bf(xa.y), f2bf(xa.z), f2bf(xa.w),
                        f2bf(xc.x), f2bf(xc.y), f2bf(xc.z), f2bf(xc.w) };
        const short* bp = wb + (size_t)r*DI + k0 + g*8;
        #pragma unroll
        for (int nf = 0; nf < 10; ++nf) {
            s16x8 bfrag = *(const s16x8*)(bp + (size_t)nf*16*DI);
            acc[nf] = __builtin_amdgcn_mfma_f32_16x16x32_bf16(afrag, bfrag, acc[nf], 0, 0, 0);
        }
    }
    const int orow = m16*16 + g*4;
    #pragma unroll
    for (int nf = 0; nf < 10; ++nf)
        #pragma unroll
        for (int j = 0; j < 4; ++j)
            part[((size_t)ks*ROWS + orow + j)*NE + nf*16 + r] = acc[nf][j];
}

// ---------------- reduce partials, emit dR(bf16) / B / C ----------------
__global__ __launch_bounds__(256) void k_split(const float* __restrict__ part,
                                               short* __restrict__ dRb,
                                               float* __restrict__ Bm,
                                               float* __restrict__ Cm) {
    int i = blockIdx.x*256 + threadIdx.x;
    if (i >= ROWS*NE) return;
    float v = 0.f;
    #pragma unroll
    for (int s = 0; s < KS1; ++s) v += part[(size_t)s*ROWS*NE + i];
    int row = i / NE, e = i - row*NE;
    if (e < DTR)            dRb[(size_t)row*DTR + e] = f2bf(v);
    else if (e < DTR + DS)  Bm[(size_t)row*DS + (e - DTR)] = v;
    else                    Cm[(size_t)row*DS + (e - DTR - DS)] = v;
}

// ---------------- GEMM2: delta = softplus(dRb @ dtwb^T + bias) — no LDS ----------------
__global__ __launch_bounds__(256) void k_gemm2(const short* __restrict__ dRb,
                                               const short* __restrict__ dtwb,
                                               const float* __restrict__ bias,
                                               float* __restrict__ delta) {
    const int wave = blockIdx.x*4 + (threadIdx.x >> 6);
    const int lane = threadIdx.x & 63;
    const int m16 = wave >> 5, nt = wave & 31;
    const int r = lane & 15, g = lane >> 4;

    s16x8 a[4];
    const short* ap = dRb + (size_t)(m16*16 + r)*DTR + g*8;
    #pragma unroll
    for (int ks = 0; ks < 4; ++ks) a[ks] = *(const s16x8*)(ap + ks*32);

    f32x4 acc[4];
    #pragma unroll
    for (int i = 0; i < 4; i++) acc[i] = (f32x4){0.f,0.f,0.f,0.f};

    #pragma unroll
    for (int nf = 0; nf < 4; ++nf) {
        const short* bp = dtwb + (size_t)(nt*64 + nf*16 + r)*DTR + g*8;
        #pragma unroll
        for (int ks = 0; ks < 4; ++ks) {
            s16x8 b = *(const s16x8*)(bp + ks*32);
            acc[nf] = __builtin_amdgcn_mfma_f32_16x16x32_bf16(a[ks], b, acc[nf], 0, 0, 0);
        }
    }
    const int orow = m16*16 + g*4;
    #pragma unroll
    for (int nf = 0; nf < 4; ++nf) {
        const int col = nt*64 + nf*16 + r;
        const float bb = bias[col];
        #pragma unroll
        for (int j = 0; j < 4; ++j) {
            float v = acc[nf][j] + bb;
            delta[(size_t)(orow + j)*DI + col] = fmaxf(v, 0.f) + log1pf(__expf(-fabsf(v)));
        }
    }
}

// ---------------- scan pass 1: DS-split x4, per-chunk summaries ----------------
// thread = (c, b, d, q): 4 states n0=4q..4q+3. summaries layout [c][b][d][n]
__global__ __launch_bounds__(256) void k_scan1(const float* __restrict__ delta,
                                               const float* __restrict__ x,
                                               const float* __restrict__ Bm,
                                               const float* __restrict__ A_log,
                                               float* __restrict__ aprod,
                                               float* __restrict__ rsum) {
    const int tid  = threadIdx.x;
    const int lane = tid & 63;
    const int w    = blockIdx.x*4 + (tid >> 6);   // 0..8191
    const int dlow = lane & 15, q = lane >> 4;
    const int d16  = w & 127;
    const int rest = w >> 7;                      // 0..63
    const int b = rest & 1, c = rest >> 1;
    const int d = d16*16 + dlow;
    const int n0 = 4*q;

    float4 Alg = *(const float4*)(A_log + (size_t)d*DS + n0);
    float An[4] = { -__expf(Alg.x), -__expf(Alg.y), -__expf(Alg.z), -__expf(Alg.w) };
    float ap[4] = {1.f,1.f,1.f,1.f}, r[4] = {0.f,0.f,0.f,0.f};

    const float* dp = delta + (size_t)b*SEQ*DI + d;
    const float* xp = x     + (size_t)b*SEQ*DI + d;
    const float* bp = Bm    + (size_t)b*SEQ*DS + n0;
    const int lbase = c*LC;
    #pragma unroll 2
    for (int tt = 0; tt < LC; ++tt) {
        const int l = lbase + tt;
        float dlt = dp[(size_t)l*DI];
        float u   = xp[(size_t)l*DI];
        float du  = dlt * u;
        float4 bv = *(const float4*)(bp + (size_t)l*DS);
        float bb[4] = {bv.x, bv.y, bv.z, bv.w};
        #pragma unroll
        for (int j = 0; j < 4; ++j) {
            float da = __expf(dlt * An[j]);
            r[j]  = fmaf(da, r[j], du * bb[j]);
            ap[j] *= da;
        }
    }
    size_t base = (((size_t)c*NBATCH + b)*DI + d)*DS + n0;
    *(float4*)(aprod + base) = (float4){ap[0], ap[1], ap[2], ap[3]};
    *(float4*)(rsum  + base) = (float4){r[0],  r[1],  r[2],  r[3]};
}

// ---------------- middle: sequential combine across chunks ----------------
__global__ __launch_bounds__(256) void k_mid(const float* __restrict__ aprod,
                                             const float* __restrict__ rsum,
                                             float* __restrict__ hin) {
    int gid = blockIdx.x*256 + threadIdx.x;   // B*DI*DS = 65536
    int n = gid & 15;
    int d = (gid >> 4) & (DI-1);
    int b = gid >> 15;
    float h = 0.f;
    for (int c = 0; c < NC; c++) {
        size_t idx = (((size_t)c*NBATCH + b)*DI + d)*DS + n;
        hin[idx] = h;
        h = fmaf(aprod[idx], h, rsum[idx]);
    }
}

// ---------------- scan pass 2: DS-split x4, butterfly-reduce y, emit ----------------
__global__ __launch_bounds__(256) void k_scan2(const float* __restrict__ delta,
                                               const float* __restrict__ x,
                                               const float* __restrict__ Bm,
                                               const float* __restrict__ Cm,
                                               const float* __restrict__ A_log,
                                               const float* __restrict__ Dv,
                                               const float* __restrict__ hin,
                                               float* __restrict__ y) {
    const int tid  = threadIdx.x;
    const int lane = tid & 63;
    const int w    = blockIdx.x*4 + (tid >> 6);
    const int dlow = lane & 15, q = lane >> 4;
    const int d16  = w & 127;
    const int rest = w >> 7;
    const int b = rest & 1, c = rest >> 1;
    const int d = d16*16 + dlow;
    const int n0 = 4*q;

    float4 Alg = *(const float4*)(A_log + (size_t)d*DS + n0);
    float An[4] = { -__expf(Alg.x), -__expf(Alg.y), -__expf(Alg.z), -__expf(Alg.w) };
    size_t base = (((size_t)c*NBATCH + b)*DI + d)*DS + n0;
    float4 hv = *(const float4*)(hin + base);
    float h[4] = {hv.x, hv.y, hv.z, hv.w};

    const float Dd = Dv[d];
    const float* dp = delta + (size_t)b*SEQ*DI + d;
    const float* xp = x     + (size_t)b*SEQ*DI + d;
    const float* bp = Bm    + (size_t)b*SEQ*DS + n0;
    const float* cp = Cm    + (size_t)b*SEQ*DS + n0;
    float* yp = y + (size_t)b*SEQ*DI + d;
    const int lbase = c*LC;
    #pragma unroll 2
    for (int tt = 0; tt < LC; ++tt) {
        const int l = lbase + tt;
        float dlt = dp[(size_t)l*DI];
        float u   = xp[(size_t)l*DI];
        float du  = dlt * u;
        float4 bv = *(const float4*)(bp + (size_t)l*DS);
        float4 cv = *(const float4*)(cp + (size_t)l*DS);
        float bb[4] = {bv.x, bv.y, bv.z, bv.w};
        float cc[4] = {cv.x, cv.y, cv.z, cv.w};
        float acc = 0.f;
        #pragma unroll
        for (int j = 0; j < 4; ++j) {
            float da = __expf(dlt * An[j]);
            h[j] = fmaf(da, h[j], du * bb[j]);
            acc  = fmaf(h[j], cc[j], acc);
        }
        acc += __shfl_xor(acc, 16);
        acc += __shfl_xor(acc, 32);
        if (q == 0) yp[(size_t)l*DI] = fmaf(u, Dd, acc);
    }
}

extern "C" void kernel_launch(void* const* d_in, const int* in_sizes, int n_in,
                              void* d_out, int out_size, void* d_ws, size_t ws_size,
                              hipStream_t stream) {
    const float* x     = (const float*)d_in[0];
    const float* A_log = (const float*)d_in[1];
    const float* Dv    = (const float*)d_in[2];
    const float* xpw   = (const float*)d_in[3];
    const float* dtw   = (const float*)d_in[4];
    const float* dtb   = (const float*)d_in[5];
    float* out = (float*)d_out;

    const size_t SCN = (size_t)NC*NBATCH*DS*DI;          // 2,097,152 floats

    float* ws    = (float*)d_ws;
    float* delta = ws;                                   // ROWS*DI floats
    float* unionR= delta + (size_t)ROWS*DI;              // union region start
    float* part  = unionR;                               // KS1*ROWS*NE = 5.24M floats (dead after k_split)
    float* aprod = unionR;                               // aliases part
    float* rsum  = aprod + SCN;
    float* hin   = rsum  + SCN;
    float* uend  = unionR + ((3*SCN > (size_t)KS1*ROWS*NE) ? 3*SCN : (size_t)KS1*ROWS*NE);
    float* Bm    = uend;                                 // ROWS*DS
    float* Cm    = Bm + (size_t)ROWS*DS;                 // ROWS*DS
    short* dRb   = (short*)(Cm + (size_t)ROWS*DS);       // ROWS*DTR shorts
    short* wb    = dRb + (size_t)ROWS*DTR;               // 160*2048 shorts
    short* dtwb  = wb  + (size_t)160*2048;               // 2048*128 shorts

    k_castw<<<576, 256, 0, stream>>>(xpw, dtw, wb, dtwb);
    k_gemm1<<<512, 256, 0, stream>>>(x, wb, part);
    k_split<<<(ROWS*NE + 255)/256, 256, 0, stream>>>(part, dRb, Bm, Cm);
    k_gemm2<<<2048, 256, 0, stream>>>(dRb, dtwb, dtb, delta);
    k_scan1<<<2048, 256, 0, stream>>>(delta, x, Bm, A_log, aprod, rsum);
    k_mid<<<256, 256, 0, stream>>>(aprod, rsum, hin);
    k_scan2<<<2048, 256, 0, stream>>>(delta, x, Bm, Cm, A_log, Dv, hin, out);
}

// Round 5
// 211.794 us; speedup vs baseline: 1.6372x; 1.0761x over previous
//
#include <hip/hip_runtime.h>
#include <hip/hip_bf16.h>
#include <math.h>

#define DI   2048      // D_INNER
#define DS   16        // D_STATE
#define DTR  128       // DT_RANK
#define NBATCH 2
#define SEQ  2048
#define ROWS (NBATCH*SEQ)   // 4096
#define NE   (DTR + 2*DS)   // 160
#define NC   32             // chunks along L
#define LC   (SEQ/NC)       // 64
#define KS1  8              // GEMM1 K-split

typedef float f32x4 __attribute__((ext_vector_type(4)));
typedef short s16x8 __attribute__((ext_vector_type(8)));
typedef short s16x4 __attribute__((ext_vector_type(4)));

__device__ inline short f2bf(float f) {
    unsigned u = __builtin_bit_cast(unsigned, f);
    u += 0x7FFFu + ((u >> 16) & 1u);   // RNE
    return (short)(u >> 16);
}

// pack 2 floats -> 2 bf16 (RNE) in one u32; should lower to v_cvt_pk_bf16_f32
__device__ inline unsigned pk2(float lo, float hi) {
    union { __hip_bfloat162 h; unsigned u; } cv;
    cv.h = __float22bfloat162_rn(float2{lo, hi});
    return cv.u;
}

// ---------------- cast weights to bf16 ----------------
__global__ __launch_bounds__(256) void k_castw(const float* __restrict__ w,
                                               const float* __restrict__ dtw,
                                               short* __restrict__ wb,
                                               short* __restrict__ dtwb) {
    int i = blockIdx.x*256 + threadIdx.x;     // 4 elems each
    if (i < 81920) {                          // 160*2048/4
        float4 v = ((const float4*)w)[i];
        s16x4 o = { f2bf(v.x), f2bf(v.y), f2bf(v.z), f2bf(v.w) };
        *(s16x4*)(wb + 4*i) = o;
    } else if (i < 147456) {                  // + 2048*128/4
        int j = i - 81920;
        float4 v = ((const float4*)dtw)[j];
        s16x4 o = { f2bf(v.x), f2bf(v.y), f2bf(v.z), f2bf(v.w) };
        *(s16x4*)(dtwb + 4*j) = o;
    }
}

// ---------------- GEMM1: part[ks] = x(bf16 in-reg) @ wb^T — no LDS, K-split 8 ----------------
__global__ __launch_bounds__(256) void k_gemm1(const float* __restrict__ x,
                                               const short* __restrict__ wb,
                                               float* __restrict__ part) {
    const int wave = blockIdx.x*4 + (threadIdx.x >> 6);   // 0..2047
    const int lane = threadIdx.x & 63;
    const int m16 = wave & 255;
    const int ks  = wave >> 8;                            // 0..7
    const int r = lane & 15, g = lane >> 4;
    f32x4 acc[10];
    #pragma unroll
    for (int i = 0; i < 10; i++) acc[i] = (f32x4){0.f,0.f,0.f,0.f};

    const float* xp = x + (size_t)(m16*16 + r)*DI + g*8;
    #pragma unroll 2
    for (int kk = 0; kk < 8; ++kk) {
        const int k0 = ks*256 + kk*32;
        float4 xa = *(const float4*)(xp + k0);
        float4 xc = *(const float4*)(xp + k0 + 4);
        union { s16x8 v; unsigned u[4]; } af;
        af.u[0] = pk2(xa.x, xa.y);
        af.u[1] = pk2(xa.z, xa.w);
        af.u[2] = pk2(xc.x, xc.y);
        af.u[3] = pk2(xc.z, xc.w);
        const short* bp = wb + (size_t)r*DI + k0 + g*8;
        #pragma unroll
        for (int nf = 0; nf < 10; ++nf) {
            s16x8 bfrag = *(const s16x8*)(bp + (size_t)nf*16*DI);
            acc[nf] = __builtin_amdgcn_mfma_f32_16x16x32_bf16(af.v, bfrag, acc[nf], 0, 0, 0);
        }
    }
    const int orow = m16*16 + g*4;
    #pragma unroll
    for (int nf = 0; nf < 10; ++nf)
        #pragma unroll
        for (int j = 0; j < 4; ++j)
            part[((size_t)ks*ROWS + orow + j)*NE + nf*16 + r] = acc[nf][j];
}

// ---------------- reduce partials, emit dR(bf16) / B / C ----------------
__global__ __launch_bounds__(256) void k_split(const float* __restrict__ part,
                                               short* __restrict__ dRb,
                                               float* __restrict__ Bm,
                                               float* __restrict__ Cm) {
    int i = blockIdx.x*256 + threadIdx.x;
    if (i >= ROWS*NE) return;
    float v = 0.f;
    #pragma unroll
    for (int s = 0; s < KS1; ++s) v += part[(size_t)s*ROWS*NE + i];
    int row = i / NE, e = i - row*NE;
    if (e < DTR)            dRb[(size_t)row*DTR + e] = f2bf(v);
    else if (e < DTR + DS)  Bm[(size_t)row*DS + (e - DTR)] = v;
    else                    Cm[(size_t)row*DS + (e - DTR - DS)] = v;
}

// ---------------- GEMM2: delta = softplus(dRb @ dtwb^T + bias) — no LDS ----------------
__global__ __launch_bounds__(256) void k_gemm2(const short* __restrict__ dRb,
                                               const short* __restrict__ dtwb,
                                               const float* __restrict__ bias,
                                               float* __restrict__ delta) {
    const int wave = blockIdx.x*4 + (threadIdx.x >> 6);
    const int lane = threadIdx.x & 63;
    const int m16 = wave >> 5, nt = wave & 31;
    const int r = lane & 15, g = lane >> 4;

    s16x8 a[4];
    const short* ap = dRb + (size_t)(m16*16 + r)*DTR + g*8;
    #pragma unroll
    for (int ks = 0; ks < 4; ++ks) a[ks] = *(const s16x8*)(ap + ks*32);

    f32x4 acc[4];
    #pragma unroll
    for (int i = 0; i < 4; i++) acc[i] = (f32x4){0.f,0.f,0.f,0.f};

    #pragma unroll
    for (int nf = 0; nf < 4; ++nf) {
        const short* bp = dtwb + (size_t)(nt*64 + nf*16 + r)*DTR + g*8;
        #pragma unroll
        for (int ks = 0; ks < 4; ++ks) {
            s16x8 b = *(const s16x8*)(bp + ks*32);
            acc[nf] = __builtin_amdgcn_mfma_f32_16x16x32_bf16(a[ks], b, acc[nf], 0, 0, 0);
        }
    }
    const int orow = m16*16 + g*4;
    #pragma unroll
    for (int nf = 0; nf < 4; ++nf) {
        const int col = nt*64 + nf*16 + r;
        const float bb = bias[col];
        #pragma unroll
        for (int j = 0; j < 4; ++j) {
            float v = acc[nf][j] + bb;
            // cheap stable softplus: max(v,0) + log(1 + exp(-|v|))
            delta[(size_t)(orow + j)*DI + col] =
                fmaxf(v, 0.f) + __logf(1.f + __expf(-fabsf(v)));
        }
    }
}

// ---------------- scan pass 1: LDS-staged chunk, DS-split x4 ----------------
// block = 4 waves, one (b,c,d64) tile. summaries layout [c][b][d][n]
__global__ __launch_bounds__(256) void k_scan1(const float* __restrict__ delta,
                                               const float* __restrict__ x,
                                               const float* __restrict__ Bm,
                                               const float* __restrict__ A_log,
                                               float* __restrict__ aprod,
                                               float* __restrict__ rsum) {
    __shared__ float ld[LC][64];
    __shared__ float lx[LC][64];
    __shared__ float lB[LC][DS];
    const int tid = threadIdx.x;
    const int bb = blockIdx.x & 31;          // d-block 0..31
    const int b  = (blockIdx.x >> 5) & 1;
    const int c  = blockIdx.x >> 6;          // 0..31
    const int d0 = bb*64;
    const int lbase = c*LC;

    // ---- coalesced staging ----
    {
        const float* dsrc = delta + ((size_t)(b*SEQ + lbase))*DI + d0;
        const float* xsrc = x     + ((size_t)(b*SEQ + lbase))*DI + d0;
        const int row = tid >> 4, col = (tid & 15)*4;
        #pragma unroll
        for (int i = 0; i < 4; i++) {
            *(float4*)&ld[row + 16*i][col] = *(const float4*)(dsrc + (size_t)(row + 16*i)*DI + col);
            *(float4*)&lx[row + 16*i][col] = *(const float4*)(xsrc + (size_t)(row + 16*i)*DI + col);
        }
        const float* bsrc = Bm + ((size_t)(b*SEQ + lbase))*DS;
        *(float4*)&lB[tid >> 2][(tid & 3)*4] = *(const float4*)(bsrc + tid*4);
    }

    const int lane = tid & 63, widx = tid >> 6;
    const int dlow = lane & 15, q = lane >> 4;
    const int dcol = widx*16 + dlow;
    const int d = d0 + dcol;
    const int n0 = 4*q;

    float4 Alg = *(const float4*)(A_log + (size_t)d*DS + n0);
    float An[4] = { -__expf(Alg.x), -__expf(Alg.y), -__expf(Alg.z), -__expf(Alg.w) };
    float ap[4] = {1.f,1.f,1.f,1.f}, r[4] = {0.f,0.f,0.f,0.f};

    __syncthreads();

    #pragma unroll 8
    for (int tt = 0; tt < LC; ++tt) {
        float dlt = ld[tt][dcol];
        float u   = lx[tt][dcol];
        float du  = dlt * u;
        float4 bv = *(const float4*)&lB[tt][n0];
        float bbv[4] = {bv.x, bv.y, bv.z, bv.w};
        #pragma unroll
        for (int j = 0; j < 4; ++j) {
            float da = __expf(dlt * An[j]);
            r[j]  = fmaf(da, r[j], du * bbv[j]);
            ap[j] *= da;
        }
    }
    size_t base = (((size_t)c*NBATCH + b)*DI + d)*DS + n0;
    *(float4*)(aprod + base) = (float4){ap[0], ap[1], ap[2], ap[3]};
    *(float4*)(rsum  + base) = (float4){r[0],  r[1],  r[2],  r[3]};
}

// ---------------- middle: sequential combine across chunks ----------------
__global__ __launch_bounds__(256) void k_mid(const float* __restrict__ aprod,
                                             const float* __restrict__ rsum,
                                             float* __restrict__ hin) {
    int gid = blockIdx.x*256 + threadIdx.x;   // B*DI*DS = 65536
    int n = gid & 15;
    int d = (gid >> 4) & (DI-1);
    int b = gid >> 15;
    float h = 0.f;
    for (int c = 0; c < NC; c++) {
        size_t idx = (((size_t)c*NBATCH + b)*DI + d)*DS + n;
        hin[idx] = h;
        h = fmaf(aprod[idx], h, rsum[idx]);
    }
}

// ---------------- scan pass 2: LDS-staged chunk, butterfly-reduce y ----------------
__global__ __launch_bounds__(256) void k_scan2(const float* __restrict__ delta,
                                               const float* __restrict__ x,
                                               const float* __restrict__ Bm,
                                               const float* __restrict__ Cm,
                                               const float* __restrict__ A_log,
                                               const float* __restrict__ Dv,
                                               const float* __restrict__ hin,
                                               float* __restrict__ y) {
    __shared__ float ld[LC][64];
    __shared__ float lx[LC][64];
    __shared__ float lB[LC][DS];
    __shared__ float lC[LC][DS];
    const int tid = threadIdx.x;
    const int bb = blockIdx.x & 31;
    const int b  = (blockIdx.x >> 5) & 1;
    const int c  = blockIdx.x >> 6;
    const int d0 = bb*64;
    const int lbase = c*LC;

    // ---- coalesced staging ----
    {
        const float* dsrc = delta + ((size_t)(b*SEQ + lbase))*DI + d0;
        const float* xsrc = x     + ((size_t)(b*SEQ + lbase))*DI + d0;
        const int row = tid >> 4, col = (tid & 15)*4;
        #pragma unroll
        for (int i = 0; i < 4; i++) {
            *(float4*)&ld[row + 16*i][col] = *(const float4*)(dsrc + (size_t)(row + 16*i)*DI + col);
            *(float4*)&lx[row + 16*i][col] = *(const float4*)(xsrc + (size_t)(row + 16*i)*DI + col);
        }
        const float* bsrc = Bm + ((size_t)(b*SEQ + lbase))*DS;
        const float* csrc = Cm + ((size_t)(b*SEQ + lbase))*DS;
        *(float4*)&lB[tid >> 2][(tid & 3)*4] = *(const float4*)(bsrc + tid*4);
        *(float4*)&lC[tid >> 2][(tid & 3)*4] = *(const float4*)(csrc + tid*4);
    }

    const int lane = tid & 63, widx = tid >> 6;
    const int dlow = lane & 15, q = lane >> 4;
    const int dcol = widx*16 + dlow;
    const int d = d0 + dcol;
    const int n0 = 4*q;

    float4 Alg = *(const float4*)(A_log + (size_t)d*DS + n0);
    float An[4] = { -__expf(Alg.x), -__expf(Alg.y), -__expf(Alg.z), -__expf(Alg.w) };
    size_t base = (((size_t)c*NBATCH + b)*DI + d)*DS + n0;
    float4 hv = *(const float4*)(hin + base);
    float h[4] = {hv.x, hv.y, hv.z, hv.w};
    const float Dd = Dv[d];
    float* yp = y + ((size_t)(b*SEQ + lbase))*DI + d;

    __syncthreads();

    #pragma unroll 8
    for (int tt = 0; tt < LC; ++tt) {
        float dlt = ld[tt][dcol];
        float u   = lx[tt][dcol];
        float du  = dlt * u;
        float4 bv = *(const float4*)&lB[tt][n0];
        float4 cv = *(const float4*)&lC[tt][n0];
        float bbv[4] = {bv.x, bv.y, bv.z, bv.w};
        float ccv[4] = {cv.x, cv.y, cv.z, cv.w};
        float acc = 0.f;
        #pragma unroll
        for (int j = 0; j < 4; ++j) {
            float da = __expf(dlt * An[j]);
            h[j] = fmaf(da, h[j], du * bbv[j]);
            acc  = fmaf(h[j], ccv[j], acc);
        }
        acc += __shfl_xor(acc, 16);
        acc += __shfl_xor(acc, 32);
        if (q == 0) yp[(size_t)tt*DI] = fmaf(u, Dd, acc);
    }
}

extern "C" void kernel_launch(void* const* d_in, const int* in_sizes, int n_in,
                              void* d_out, int out_size, void* d_ws, size_t ws_size,
                              hipStream_t stream) {
    const float* x     = (const float*)d_in[0];
    const float* A_log = (const float*)d_in[1];
    const float* Dv    = (const float*)d_in[2];
    const float* xpw   = (const float*)d_in[3];
    const float* dtw   = (const float*)d_in[4];
    const float* dtb   = (const float*)d_in[5];
    float* out = (float*)d_out;

    const size_t SCN = (size_t)NC*NBATCH*DS*DI;          // 2,097,152 floats

    float* ws    = (float*)d_ws;
    float* delta = ws;                                   // ROWS*DI floats
    float* unionR= delta + (size_t)ROWS*DI;              // union region start
    float* part  = unionR;                               // KS1*ROWS*NE floats (dead after k_split)
    float* aprod = unionR;                               // aliases part
    float* rsum  = aprod + SCN;
    float* hin   = rsum  + SCN;
    float* uend  = unionR + ((3*SCN > (size_t)KS1*ROWS*NE) ? 3*SCN : (size_t)KS1*ROWS*NE);
    float* Bm    = uend;                                 // ROWS*DS
    float* Cm    = Bm + (size_t)ROWS*DS;                 // ROWS*DS
    short* dRb   = (short*)(Cm + (size_t)ROWS*DS);       // ROWS*DTR shorts
    short* wb    = dRb + (size_t)ROWS*DTR;               // 160*2048 shorts
    short* dtwb  = wb  + (size_t)160*2048;               // 2048*128 shorts

    k_castw<<<576, 256, 0, stream>>>(xpw, dtw, wb, dtwb);
    k_gemm1<<<512, 256, 0, stream>>>(x, wb, part);
    k_split<<<(ROWS*NE + 255)/256, 256, 0, stream>>>(part, dRb, Bm, Cm);
    k_gemm2<<<2048, 256, 0, stream>>>(dRb, dtwb, dtb, delta);
    k_scan1<<<2048, 256, 0, stream>>>(delta, x, Bm, A_log, aprod, rsum);
    k_mid<<<256, 256, 0, stream>>>(aprod, rsum, hin);
    k_scan2<<<2048, 256, 0, stream>>>(delta, x, Bm, Cm, A_log, Dv, hin, out);
}